// Round 9
// baseline (239.749 us; speedup 1.0000x reference)
//
#include <hip/hip_runtime.h>
#include <hip/hip_bf16.h>

#define BATCH 4
#define SEQ   2048
#define DIN   1024
#define DOUT  1024
#define N3    3072
#define MTOT  (BATCH*SEQ)

typedef __hip_bfloat16 bf16;
typedef __attribute__((ext_vector_type(8))) short bf16x8;
typedef __attribute__((ext_vector_type(4))) float f32x4;

#define MFMA(a,b,c) __builtin_amdgcn_mfma_f32_16x16x32_bf16(a,b,c,0,0,0)

union pack4 { bf16 h[4]; uint2 u2; };
union pack8 { bf16 h[8]; bf16x8 v; };

// async 16B global->LDS (DMA, no VGPR round-trip)
__device__ __forceinline__ void gl16(const bf16* g, bf16* l)
{
    __builtin_amdgcn_global_load_lds(
        (const __attribute__((address_space(1))) void*)g,
        (__attribute__((address_space(3))) void*)l, 16, 0, 0);
}

// ---------------- fused conversions ----------------

__global__ __launch_bounds__(256)
void k_prep(const float* __restrict__ x, const float* __restrict__ Wq,
            const float* __restrict__ Wk, const float* __restrict__ Wv,
            bf16* __restrict__ xb, bf16* __restrict__ Wt)
{
    __shared__ bf16 t[64][68];
    const int bid = blockIdx.x;
    if (bid < 8192) {
        long i = ((long)bid * 256 + threadIdx.x) * 4;
        float4 v = *(const float4*)(x + i);
        pack4 o;
        o.h[0] = __float2bfloat16(v.x);
        o.h[1] = __float2bfloat16(v.y);
        o.h[2] = __float2bfloat16(v.z);
        o.h[3] = __float2bfloat16(v.w);
        *(uint2*)(xb + i) = o.u2;
        return;
    }
    const int idx = bid - 8192;                // 0..767
    const int mat = idx >> 8;
    const int rem = idx & 255;
    const int k0 = (rem >> 4) * 64, n0 = (rem & 15) * 64;
    const float* W = (mat == 0) ? Wq : ((mat == 1) ? Wk : Wv);
#pragma unroll
    for (int p = 0; p < 4; ++p) {
        int kr = p * 16 + (threadIdx.x >> 4);
        int c4 = (threadIdx.x & 15) * 4;
        float4 v = *(const float4*)&W[(long)(k0 + kr) * DOUT + n0 + c4];
        t[c4 + 0][kr] = __float2bfloat16(v.x);
        t[c4 + 1][kr] = __float2bfloat16(v.y);
        t[c4 + 2][kr] = __float2bfloat16(v.z);
        t[c4 + 3][kr] = __float2bfloat16(v.w);
    }
    __syncthreads();
    bf16* O = Wt + (long)mat * DIN * DOUT;
#pragma unroll
    for (int i = 0; i < 2; ++i) {
        int l = threadIdx.x + i * 256;
        int n = l >> 3, c8 = (l & 7) * 8;
        pack8 o;
#pragma unroll
        for (int j = 0; j < 8; ++j) o.h[j] = t[n][c8 + j];
        *(bf16x8*)&O[(long)(n0 + n) * DIN + k0 + c8] = o.v;
    }
}

// ---------------- single-buffer GEMM core, BK=64 ----------------

__device__ __forceinline__ void gemm_core(
    const bf16* __restrict__ Ab, long lda,
    const bf16* __restrict__ Bb, long ldb,
    int nk, bf16* __restrict__ As, bf16* __restrict__ Bs,
    f32x4 acc[4][4])
{
    const int tid  = threadIdx.x;
    const int lane = tid & 63;
    const int wave = tid >> 6;
    const int wm = (wave >> 1) * 64;
    const int wn = (wave & 1) * 64;
    const int r  = lane & 15;
    const int qd = lane >> 4;

    const int row0 = tid >> 3;
    const int c    = (tid & 7) ^ (row0 & 7);
    const long aoff = (long)row0 * lda + c * 8;
    const long boff = (long)row0 * ldb + c * 8;
    const long astep = 32 * lda, bstep = 32 * ldb;
    bf16* dA = &As[tid * 8];
    bf16* dB = &Bs[tid * 8];

    for (int kk = 0; kk < nk; ++kk) {
        const bf16* A = Ab + kk * 64 + aoff;
        const bf16* B = Bb + kk * 64 + boff;
#pragma unroll
        for (int i = 0; i < 4; ++i) {
            gl16(A + i * astep, dA + i * 2048);
            gl16(B + i * bstep, dB + i * 2048);
        }
        __syncthreads();
#pragma unroll
        for (int ks = 0; ks < 2; ++ks) {
            const int slot = ((ks * 4 + qd) ^ (r & 7)) * 8;
            bf16x8 af[4], bv[4];
#pragma unroll
            for (int mi = 0; mi < 4; ++mi)
                af[mi] = *(const bf16x8*)&As[(wm + mi * 16 + r) * 64 + slot];
#pragma unroll
            for (int ni = 0; ni < 4; ++ni)
                bv[ni] = *(const bf16x8*)&Bs[(wn + ni * 16 + r) * 64 + slot];
#pragma unroll
            for (int mi = 0; mi < 4; ++mi)
#pragma unroll
                for (int ni = 0; ni < 4; ++ni)
                    acc[mi][ni] = MFMA(af[mi], bv[ni], acc[mi][ni]);
        }
        __syncthreads();
    }
}

// ---------------- Q|K projection (n-tiles 0..15) ----------------

__global__ __launch_bounds__(256)
void k_gemm_qk(const bf16* __restrict__ xb, const bf16* __restrict__ Wt,
               bf16* __restrict__ QK)
{
    __shared__ __align__(16) bf16 smem[17408];
    bf16* As = smem;
    bf16* Bs = smem + 8192;
    const int m0 = blockIdx.y * 128, n0 = blockIdx.x * 128;
    f32x4 acc[4][4] = {};
    gemm_core(xb + (long)m0 * DIN, DIN, Wt + (long)n0 * DIN, DIN, DIN / 64, As, Bs, acc);

    const int tid = threadIdx.x;
    const int lane = tid & 63, wave = tid >> 6;
    const int wm = (wave >> 1) * 64, wn = (wave & 1) * 64;
    const int r = lane & 15, qd = lane >> 4;
    const int ld = 136;
    bf16* T = smem;
#pragma unroll
    for (int mi = 0; mi < 4; ++mi)
#pragma unroll
        for (int ni = 0; ni < 4; ++ni)
#pragma unroll
            for (int j = 0; j < 4; ++j)
                T[(wm + mi * 16 + qd * 4 + j) * ld + wn + ni * 16 + r] =
                    __float2bfloat16(acc[mi][ni][j]);
    __syncthreads();
#pragma unroll
    for (int i = 0; i < 8; ++i) {
        int l = tid + i * 256;
        int rr = l >> 4, c8 = (l & 15) * 8;
        bf16x8 v = *(const bf16x8*)&T[rr * ld + c8];
        *(bf16x8*)&QK[(long)(m0 + rr) * 2048 + n0 + c8] = v;
    }
}

// ---------------- V projection (n-tiles 16..23) -> Vt[b][d][s] ---------

__global__ __launch_bounds__(256)
void k_gemm_v(const bf16* __restrict__ xb, const bf16* __restrict__ Wt,
              bf16* __restrict__ Vt)
{
    __shared__ __align__(16) bf16 smem[17408];
    bf16* As = smem;
    bf16* Bs = smem + 8192;
    const int m0 = blockIdx.y * 128;
    const int n0 = 2048 + blockIdx.x * 128;        // V columns
    f32x4 acc[4][4] = {};
    gemm_core(xb + (long)m0 * DIN, DIN, Wt + (long)n0 * DIN, DIN, DIN / 64, As, Bs, acc);

    const int tid = threadIdx.x;
    const int lane = tid & 63, wave = tid >> 6;
    const int wm = (wave >> 1) * 64, wn = (wave & 1) * 64;
    const int r = lane & 15, qd = lane >> 4;
    const int ld = 136;
    bf16* T = smem;
#pragma unroll
    for (int mi = 0; mi < 4; ++mi)
#pragma unroll
        for (int ni = 0; ni < 4; ++ni) {
            pack4 p;
#pragma unroll
            for (int j = 0; j < 4; ++j) p.h[j] = __float2bfloat16(acc[mi][ni][j]);
            int d_l = wn + ni * 16 + r;
            int s_l = wm + mi * 16 + qd * 4;
            *(uint2*)&T[d_l * ld + s_l] = p.u2;
        }
    __syncthreads();
    const int n0v = n0 - 2048;
    const int bb = m0 >> 11;
    const int s0 = m0 & 2047;
    bf16* Ob = Vt + (long)bb * DOUT * SEQ + s0;
#pragma unroll
    for (int p = 0; p < 8; ++p) {
        int l = tid + p * 256;
        int d = l >> 4, s8 = (l & 15) * 8;
        bf16x8 vv = *(const bf16x8*)&T[d * ld + s8];
        *(bf16x8*)&Ob[(long)(n0v + d) * SEQ + s8] = vv;
    }
}

// ---------------- scores + exp + row-sum (R6 config) ----------------

__global__ __launch_bounds__(256, 3)
void k_gemm_scores(const bf16* __restrict__ QK, bf16* __restrict__ P,
                   float* __restrict__ rowSum)
{
    const int b = blockIdx.z, qt = blockIdx.y, kt = blockIdx.x;
    if (kt > qt) return;
    __shared__ __align__(16) bf16 As[128 * 64];
    __shared__ __align__(16) bf16 Bs[128 * 64];
    const bf16* A  = QK + (long)b * SEQ * 2048;
    const bf16* Bt = A + 1024;
    f32x4 acc[4][4] = {};
    gemm_core(A + (long)qt * 128 * 2048, 2048, Bt + (long)kt * 128 * 2048, 2048,
              DIN / 64, As, Bs, acc);

    bf16* Pb = P + (long)b * SEQ * SEQ;
    float* RS = rowSum + b * SEQ;
    const int lane = threadIdx.x & 63, wave = threadIdx.x >> 6;
    const int wm = (wave >> 1) * 64, wn = (wave & 1) * 64;
    const int r = lane & 15, qd = lane >> 4;

    float rp[4][4];
#pragma unroll
    for (int mi = 0; mi < 4; ++mi)
#pragma unroll
        for (int j = 0; j < 4; ++j) rp[mi][j] = 0.f;

#pragma unroll
    for (int mi = 0; mi < 4; ++mi)
#pragma unroll
        for (int ni = 0; ni < 4; ++ni)
#pragma unroll
            for (int j = 0; j < 4; ++j) {
                int row = qt * 128 + wm + mi * 16 + qd * 4 + j;
                int col = kt * 128 + wn + ni * 16 + r;
                float e = (col > row) ? 0.f : __expf(acc[mi][ni][j] * 0.03125f);
                rp[mi][j] += e;
                Pb[(long)row * SEQ + col] = __float2bfloat16(e);
            }
#pragma unroll
    for (int d = 1; d < 16; d <<= 1)
#pragma unroll
        for (int mi = 0; mi < 4; ++mi)
#pragma unroll
            for (int j = 0; j < 4; ++j)
                rp[mi][j] += __shfl_xor(rp[mi][j], d, 64);
    if (r == 0) {
#pragma unroll
        for (int mi = 0; mi < 4; ++mi)
#pragma unroll
            for (int j = 0; j < 4; ++j) {
                int row = qt * 128 + wm + mi * 16 + qd * 4 + j;
                atomicAdd(&RS[row], rp[mi][j]);
            }
    }
}

// ---------------- PV: O = (P @ V) / rowSum (R6 config) ----------------

__global__ __launch_bounds__(256, 3)
void k_gemm_pv(const bf16* __restrict__ P, const bf16* __restrict__ Vt,
               const float* __restrict__ rowSum, float* __restrict__ O)
{
    const int b = blockIdx.z, nt = blockIdx.x;
    const int qt = (SEQ / 128 - 1) - blockIdx.y;   // heavy (large nk) first
    __shared__ __align__(16) bf16 As[128 * 64];
    __shared__ __align__(16) bf16 Bs[128 * 64];
    const bf16* A  = P + (long)b * SEQ * SEQ + (long)qt * 128 * SEQ;
    const bf16* Bt = Vt + (long)b * DOUT * SEQ;
    const int nk = (qt + 1) * 2;
    f32x4 acc[4][4] = {};
    gemm_core(A, SEQ, Bt + (long)nt * 128 * SEQ, SEQ, nk, As, Bs, acc);

    float* Ob = O + (long)b * SEQ * DOUT;
    const float* RS = rowSum + b * SEQ;
    const int lane = threadIdx.x & 63, wave = threadIdx.x >> 6;
    const int wm = (wave >> 1) * 64, wn = (wave & 1) * 64;
    const int r = lane & 15, qd = lane >> 4;
#pragma unroll
    for (int mi = 0; mi < 4; ++mi)
#pragma unroll
        for (int j = 0; j < 4; ++j) {
            int row = qt * 128 + wm + mi * 16 + qd * 4 + j;
            float inv = 1.0f / RS[row];
#pragma unroll
            for (int ni = 0; ni < 4; ++ni) {
                int col = nt * 128 + wn + ni * 16 + r;
                Ob[(long)row * DOUT + col] = acc[mi][ni][j] * inv;
            }
        }
}

// ---------------- launch ----------------

extern "C" void kernel_launch(void* const* d_in, const int* in_sizes, int n_in,
                              void* d_out, int out_size, void* d_ws, size_t ws_size,
                              hipStream_t stream)
{
    const float* x  = (const float*)d_in[0];
    const float* Wq = (const float*)d_in[1];
    const float* Wk = (const float*)d_in[2];
    const float* Wv = (const float*)d_in[3];
    float* out = (float*)d_out;

    char* ws = (char*)d_ws;
    bf16*  xb = (bf16*)(ws);                        // 16 MiB
    bf16*  Wt = (bf16*)(ws + 16777216);             //  6 MiB
    bf16*  QK = (bf16*)(ws + 23068672);             // 32 MiB
    bf16*  Vt = (bf16*)(ws + 56623104);             // 16 MiB
    bf16*  P  = (bf16*)(ws + 73400320);             // 32 MiB
    float* RS = (float*)(ws + 106954752);           // 32 KiB

    hipMemsetAsync(RS, 0, BATCH * SEQ * sizeof(float), stream);
    k_prep<<<dim3(8192 + 768), 256, 0, stream>>>(x, Wq, Wk, Wv, xb, Wt);
    k_gemm_qk<<<dim3(2048 / 128, MTOT / 128), 256, 0, stream>>>(xb, Wt, QK);
    k_gemm_v <<<dim3(1024 / 128, MTOT / 128), 256, 0, stream>>>(xb, Wt, Vt);
    k_gemm_scores<<<dim3(SEQ / 128, SEQ / 128, BATCH), 256, 0, stream>>>(QK, P, RS);
    k_gemm_pv<<<dim3(DOUT / 128, SEQ / 128, BATCH), 256, 0, stream>>>(P, Vt, RS, out);
}

// Round 10
// 229.158 us; speedup vs baseline: 1.0462x; 1.0462x over previous
//
#include <hip/hip_runtime.h>
#include <hip/hip_bf16.h>

#define BATCH 4
#define SEQ   2048
#define DIN   1024
#define DOUT  1024
#define N3    3072
#define MTOT  (BATCH*SEQ)

typedef __hip_bfloat16 bf16;
typedef __attribute__((ext_vector_type(8))) short bf16x8;
typedef __attribute__((ext_vector_type(4))) float f32x4;

#define MFMA(a,b,c) __builtin_amdgcn_mfma_f32_16x16x32_bf16(a,b,c,0,0,0)

union pack4 { bf16 h[4]; uint2 u2; };
union pack8 { bf16 h[8]; bf16x8 v; };

// async 16B global->LDS (DMA, no VGPR round-trip)
__device__ __forceinline__ void gl16(const bf16* g, bf16* l)
{
    __builtin_amdgcn_global_load_lds(
        (const __attribute__((address_space(1))) void*)g,
        (__attribute__((address_space(3))) void*)l, 16, 0, 0);
}

// ---------------- fused conversions + RS zero ----------------
// blocks [0,8192): x fp32->bf16 ; blocks [0,32) ALSO zero rowSum (8 KB each)
// blocks [8192,8960): W transpose tiles

__global__ __launch_bounds__(256)
void k_prep(const float* __restrict__ x, const float* __restrict__ Wq,
            const float* __restrict__ Wk, const float* __restrict__ Wv,
            bf16* __restrict__ xb, bf16* __restrict__ Wt,
            float* __restrict__ RS)
{
    __shared__ bf16 t[64][68];
    const int bid = blockIdx.x;
    if (bid < 8192) {
        if (bid < 32) RS[bid * 256 + threadIdx.x] = 0.f;   // 8192 floats total
        long i = ((long)bid * 256 + threadIdx.x) * 4;
        float4 v = *(const float4*)(x + i);
        pack4 o;
        o.h[0] = __float2bfloat16(v.x);
        o.h[1] = __float2bfloat16(v.y);
        o.h[2] = __float2bfloat16(v.z);
        o.h[3] = __float2bfloat16(v.w);
        *(uint2*)(xb + i) = o.u2;
        return;
    }
    const int idx = bid - 8192;                // 0..767
    const int mat = idx >> 8;
    const int rem = idx & 255;
    const int k0 = (rem >> 4) * 64, n0 = (rem & 15) * 64;
    const float* W = (mat == 0) ? Wq : ((mat == 1) ? Wk : Wv);
#pragma unroll
    for (int p = 0; p < 4; ++p) {
        int kr = p * 16 + (threadIdx.x >> 4);
        int c4 = (threadIdx.x & 15) * 4;
        float4 v = *(const float4*)&W[(long)(k0 + kr) * DOUT + n0 + c4];
        t[c4 + 0][kr] = __float2bfloat16(v.x);
        t[c4 + 1][kr] = __float2bfloat16(v.y);
        t[c4 + 2][kr] = __float2bfloat16(v.z);
        t[c4 + 3][kr] = __float2bfloat16(v.w);
    }
    __syncthreads();
    bf16* O = Wt + (long)mat * DIN * DOUT;
#pragma unroll
    for (int i = 0; i < 2; ++i) {
        int l = threadIdx.x + i * 256;
        int n = l >> 3, c8 = (l & 7) * 8;
        pack8 o;
#pragma unroll
        for (int j = 0; j < 8; ++j) o.h[j] = t[n][c8 + j];
        *(bf16x8*)&O[(long)(n0 + n) * DIN + k0 + c8] = o.v;
    }
}

// ---------------- single-buffer GEMM core, BK=64 ----------------

__device__ __forceinline__ void gemm_core(
    const bf16* __restrict__ Ab, long lda,
    const bf16* __restrict__ Bb, long ldb,
    int nk, bf16* __restrict__ As, bf16* __restrict__ Bs,
    f32x4 acc[4][4])
{
    const int tid  = threadIdx.x;
    const int lane = tid & 63;
    const int wave = tid >> 6;
    const int wm = (wave >> 1) * 64;
    const int wn = (wave & 1) * 64;
    const int r  = lane & 15;
    const int qd = lane >> 4;

    const int row0 = tid >> 3;
    const int c    = (tid & 7) ^ (row0 & 7);
    const long aoff = (long)row0 * lda + c * 8;
    const long boff = (long)row0 * ldb + c * 8;
    const long astep = 32 * lda, bstep = 32 * ldb;
    bf16* dA = &As[tid * 8];
    bf16* dB = &Bs[tid * 8];

    for (int kk = 0; kk < nk; ++kk) {
        const bf16* A = Ab + kk * 64 + aoff;
        const bf16* B = Bb + kk * 64 + boff;
#pragma unroll
        for (int i = 0; i < 4; ++i) {
            gl16(A + i * astep, dA + i * 2048);
            gl16(B + i * bstep, dB + i * 2048);
        }
        __syncthreads();
#pragma unroll
        for (int ks = 0; ks < 2; ++ks) {
            const int slot = ((ks * 4 + qd) ^ (r & 7)) * 8;
            bf16x8 af[4], bv[4];
#pragma unroll
            for (int mi = 0; mi < 4; ++mi)
                af[mi] = *(const bf16x8*)&As[(wm + mi * 16 + r) * 64 + slot];
#pragma unroll
            for (int ni = 0; ni < 4; ++ni)
                bv[ni] = *(const bf16x8*)&Bs[(wn + ni * 16 + r) * 64 + slot];
#pragma unroll
            for (int mi = 0; mi < 4; ++mi)
#pragma unroll
                for (int ni = 0; ni < 4; ++ni)
                    acc[mi][ni] = MFMA(af[mi], bv[ni], acc[mi][ni]);
        }
        __syncthreads();
    }
}

// ---------------- QKV projection (merged, R7 proven form) ----------------

__global__ __launch_bounds__(256)
void k_gemm_qkv(const bf16* __restrict__ xb, const bf16* __restrict__ Wt,
                bf16* __restrict__ QK, bf16* __restrict__ Vt)
{
    __shared__ __align__(16) bf16 smem[17408];
    bf16* As = smem;
    bf16* Bs = smem + 8192;
    const int m0 = blockIdx.y * 128, n0 = blockIdx.x * 128;
    f32x4 acc[4][4] = {};
    gemm_core(xb + (long)m0 * DIN, DIN, Wt + (long)n0 * DIN, DIN, DIN / 64, As, Bs, acc);

    const int tid = threadIdx.x;
    const int lane = tid & 63, wave = tid >> 6;
    const int wm = (wave >> 1) * 64, wn = (wave & 1) * 64;
    const int r = lane & 15, qd = lane >> 4;
    const int ld = 136;
    bf16* T = smem;

    if (n0 < 2048) {                               // Q|K via LDS re-block
#pragma unroll
        for (int mi = 0; mi < 4; ++mi)
#pragma unroll
            for (int ni = 0; ni < 4; ++ni)
#pragma unroll
                for (int j = 0; j < 4; ++j)
                    T[(wm + mi * 16 + qd * 4 + j) * ld + wn + ni * 16 + r] =
                        __float2bfloat16(acc[mi][ni][j]);
        __syncthreads();
#pragma unroll
        for (int i = 0; i < 8; ++i) {
            int l = tid + i * 256;
            int rr = l >> 4, c8 = (l & 15) * 8;
            bf16x8 v = *(const bf16x8*)&T[rr * ld + c8];
            *(bf16x8*)&QK[(long)(m0 + rr) * 2048 + n0 + c8] = v;
        }
    } else {                                       // V: transpose via LDS
#pragma unroll
        for (int mi = 0; mi < 4; ++mi)
#pragma unroll
            for (int ni = 0; ni < 4; ++ni) {
                pack4 p;
#pragma unroll
                for (int j = 0; j < 4; ++j) p.h[j] = __float2bfloat16(acc[mi][ni][j]);
                int d_l = wn + ni * 16 + r;
                int s_l = wm + mi * 16 + qd * 4;
                *(uint2*)&T[d_l * ld + s_l] = p.u2;
            }
        __syncthreads();
        const int n0v = n0 - 2048;
        const int bb = m0 >> 11;
        const int s0 = m0 & 2047;
        bf16* Ob = Vt + (long)bb * DOUT * SEQ + s0;
#pragma unroll
        for (int p = 0; p < 8; ++p) {
            int l = tid + p * 256;
            int d = l >> 4, s8 = (l & 15) * 8;
            bf16x8 vv = *(const bf16x8*)&T[d * ld + s8];
            *(bf16x8*)&Ob[(long)(n0v + d) * SEQ + s8] = vv;
        }
    }
}

// ---------------- scores + exp + row-sum (triangular grid) ----------------

__global__ __launch_bounds__(256, 3)
void k_gemm_scores(const bf16* __restrict__ QK, bf16* __restrict__ P,
                   float* __restrict__ rowSum)
{
    const int b = blockIdx.z;
    int i = blockIdx.x;
    int qt = (int)((sqrtf(8.f * i + 1.f) - 1.f) * 0.5f);
    if (qt * (qt + 1) / 2 > i) --qt;
    else if ((qt + 1) * (qt + 2) / 2 <= i) ++qt;
    const int kt = i - qt * (qt + 1) / 2;

    __shared__ __align__(16) bf16 As[128 * 64];
    __shared__ __align__(16) bf16 Bs[128 * 64];
    const bf16* A  = QK + (long)b * SEQ * 2048;
    const bf16* Bt = A + 1024;
    f32x4 acc[4][4] = {};
    gemm_core(A + (long)qt * 128 * 2048, 2048, Bt + (long)kt * 128 * 2048, 2048,
              DIN / 64, As, Bs, acc);

    bf16* Pb = P + (long)b * SEQ * SEQ;
    float* RS = rowSum + b * SEQ;
    const int lane = threadIdx.x & 63, wave = threadIdx.x >> 6;
    const int wm = (wave >> 1) * 64, wn = (wave & 1) * 64;
    const int r = lane & 15, qd = lane >> 4;

    float rp[4][4];
#pragma unroll
    for (int mi = 0; mi < 4; ++mi)
#pragma unroll
        for (int j = 0; j < 4; ++j) rp[mi][j] = 0.f;

#pragma unroll
    for (int mi = 0; mi < 4; ++mi)
#pragma unroll
        for (int ni = 0; ni < 4; ++ni)
#pragma unroll
            for (int j = 0; j < 4; ++j) {
                int row = qt * 128 + wm + mi * 16 + qd * 4 + j;
                int col = kt * 128 + wn + ni * 16 + r;
                float e = (col > row) ? 0.f : __expf(acc[mi][ni][j] * 0.03125f);
                rp[mi][j] += e;
                Pb[(long)row * SEQ + col] = __float2bfloat16(e);
            }
#pragma unroll
    for (int d = 1; d < 16; d <<= 1)
#pragma unroll
        for (int mi = 0; mi < 4; ++mi)
#pragma unroll
            for (int j = 0; j < 4; ++j)
                rp[mi][j] += __shfl_xor(rp[mi][j], d, 64);
    if (r == 0) {
#pragma unroll
        for (int mi = 0; mi < 4; ++mi)
#pragma unroll
            for (int j = 0; j < 4; ++j) {
                int row = qt * 128 + wm + mi * 16 + qd * 4 + j;
                atomicAdd(&RS[row], rp[mi][j]);
            }
    }
}

// ---------------- PV: O = (P @ V) / rowSum ----------------

__global__ __launch_bounds__(256, 3)
void k_gemm_pv(const bf16* __restrict__ P, const bf16* __restrict__ Vt,
               const float* __restrict__ rowSum, float* __restrict__ O)
{
    const int b = blockIdx.z, nt = blockIdx.x;
    const int qt = (SEQ / 128 - 1) - blockIdx.y;   // heavy (large nk) first
    __shared__ __align__(16) bf16 As[128 * 64];
    __shared__ __align__(16) bf16 Bs[128 * 64];
    const bf16* A  = P + (long)b * SEQ * SEQ + (long)qt * 128 * SEQ;
    const bf16* Bt = Vt + (long)b * DOUT * SEQ;
    const int nk = (qt + 1) * 2;
    f32x4 acc[4][4] = {};
    gemm_core(A, SEQ, Bt + (long)nt * 128 * SEQ, SEQ, nk, As, Bs, acc);

    float* Ob = O + (long)b * SEQ * DOUT;
    const float* RS = rowSum + b * SEQ;
    const int lane = threadIdx.x & 63, wave = threadIdx.x >> 6;
    const int wm = (wave >> 1) * 64, wn = (wave & 1) * 64;
    const int r = lane & 15, qd = lane >> 4;
#pragma unroll
    for (int mi = 0; mi < 4; ++mi)
#pragma unroll
        for (int j = 0; j < 4; ++j) {
            int row = qt * 128 + wm + mi * 16 + qd * 4 + j;
            float inv = 1.0f / RS[row];
#pragma unroll
            for (int ni = 0; ni < 4; ++ni) {
                int col = nt * 128 + wn + ni * 16 + r;
                Ob[(long)row * DOUT + col] = acc[mi][ni][j] * inv;
            }
        }
}

// ---------------- launch ----------------

extern "C" void kernel_launch(void* const* d_in, const int* in_sizes, int n_in,
                              void* d_out, int out_size, void* d_ws, size_t ws_size,
                              hipStream_t stream)
{
    const float* x  = (const float*)d_in[0];
    const float* Wq = (const float*)d_in[1];
    const float* Wk = (const float*)d_in[2];
    const float* Wv = (const float*)d_in[3];
    float* out = (float*)d_out;

    char* ws = (char*)d_ws;
    bf16*  xb = (bf16*)(ws);                        // 16 MiB
    bf16*  Wt = (bf16*)(ws + 16777216);             //  6 MiB
    bf16*  QK = (bf16*)(ws + 23068672);             // 32 MiB
    bf16*  Vt = (bf16*)(ws + 56623104);             // 16 MiB
    bf16*  P  = (bf16*)(ws + 73400320);             // 32 MiB
    float* RS = (float*)(ws + 106954752);           // 32 KiB

    k_prep<<<dim3(8192 + 768), 256, 0, stream>>>(x, Wq, Wk, Wv, xb, Wt, RS);
    k_gemm_qkv<<<dim3(N3 / 128, MTOT / 128), 256, 0, stream>>>(xb, Wt, QK, Vt);
    k_gemm_scores<<<dim3(136, 1, BATCH), 256, 0, stream>>>(QK, P, RS);
    k_gemm_pv<<<dim3(DOUT / 128, SEQ / 128, BATCH), 256, 0, stream>>>(P, Vt, RS, out);
}